// Round 3
// baseline (3437.484 us; speedup 1.0000x reference)
//
#include <hip/hip_runtime.h>

// GAT pipeline, MI355X (gfx950) — round 3: device-side dtype detection.
// Forensics: with bf16 inputs the round-2 pipeline has no NaN path, yet output
// was NaN => float inputs are f32 (as the reference declares) and/or edges are
// int64. This round detects storage dtypes on-device and branches:
//  - f32-vs-bf16: even-indexed ushorts of an f32 buffer are mantissa junk
//    (~15% plausible bf16 exponents); of a bf16 buffer they are real values
//    (~100%). Probe >=96 even ushorts per tensor.
//  - int64-vs-int32 edges: odd int32 words all zero iff int64 (ids < 2^31).
// Output is written in x's detected dtype.

#define NNODES 100000
#define NEDGES 6400000
#define DIN    768
#define DH1    512
#define DH2    256
#define NEG_SLOPE 0.2f

typedef __bf16 bf16x8 __attribute__((ext_vector_type(8)));
typedef float  f32x4  __attribute__((ext_vector_type(4)));

__device__ __forceinline__ float bf2f(unsigned short h) {
    return __uint_as_float(((unsigned)h) << 16);
}
__device__ __forceinline__ unsigned short f2bf(float f) {
    unsigned u = __float_as_uint(f);
    unsigned r = u + 0x7FFFu + ((u >> 16) & 1u);   // round-nearest-even
    return (unsigned short)(r >> 16);
}
__device__ __forceinline__ float ldf(const void* p, int i, int isf32) {
    return isf32 ? ((const float*)p)[i] : bf2f(((const unsigned short*)p)[i]);
}
__device__ __forceinline__ uint4 packbf8(const float* p) {
    float4 u = *(const float4*)p;
    float4 v = *(const float4*)(p + 4);
    uint4 r;
    r.x = (unsigned)f2bf(u.x) | ((unsigned)f2bf(u.y) << 16);
    r.y = (unsigned)f2bf(u.z) | ((unsigned)f2bf(u.w) << 16);
    r.z = (unsigned)f2bf(v.x) | ((unsigned)f2bf(v.y) << 16);
    r.w = (unsigned)f2bf(v.z) | ((unsigned)f2bf(v.w) << 16);
    return r;
}

// flags: [0]=x_f32 [1]=We1_f32 [2]=We2_f32 [3]=Wlin_f32 [4]=Watt_f32
//        [5]=edge_i64 [15]=0 constant
__global__ void detect_dtypes(const unsigned short* x, const unsigned short* we1,
                              const unsigned short* we2, const unsigned short* wlin,
                              const unsigned short* watt, const int* ei, int* flags) {
    __shared__ int cnt;
    int b = blockIdx.x, t = threadIdx.x;
    if (t == 0) cnt = 0;
    __syncthreads();
    if (b < 5) {
        const unsigned short* p = (b == 0) ? x : (b == 1) ? we1 : (b == 2) ? we2
                                  : (b == 3) ? wlin : watt;
        int K = (b == 4) ? 96 : 512;
        int c = 0;
        for (int i = t; i < K; i += 256) {
            int e = (p[2 * i] >> 7) & 0xFF;
            if (e >= 0x66 && e <= 0x8C) c++;
        }
        atomicAdd(&cnt, c);
        __syncthreads();
        if (t == 0) flags[b] = (cnt * 10 < K * 6) ? 1 : 0;
    } else {
        int c = 0;
        for (int i = t; i < 2048; i += 256)
            if (ei[2 * i + 1] != 0) c++;
        atomicAdd(&cnt, c);
        __syncthreads();
        if (t == 0) { flags[5] = (cnt == 0) ? 1 : 0; flags[15] = 0; }
    }
}

__global__ void transpose_conv(const void* in, unsigned short* out, int K, int N,
                               const int* flags, int fidx) {
    int f32 = flags[fidx];
    int idx = blockIdx.x * 256 + threadIdx.x;
    if (idx >= K * N) return;
    int k = idx / N, n = idx - k * N;
    unsigned short v = f32 ? f2bf(((const float*)in)[idx])
                           : ((const unsigned short*)in)[idx];
    out[(size_t)n * K + k] = v;
}

template <bool RELU>
__global__ __launch_bounds__(256)
void gemm_bt(const void* __restrict__ A,
             const unsigned short* __restrict__ Bt,
             const unsigned short* __restrict__ bias,
             unsigned short* __restrict__ C,
             int M, int K, int N, const int* flags, int aidx) {
    __shared__ unsigned short sA[128 * 32];
    __shared__ unsigned short sB[128 * 32];
    const int af32 = flags[aidx];
    const int tid = threadIdx.x;
    const int m0 = blockIdx.x * 128;
    const int n0 = blockIdx.y * 128;

    const int srow = tid >> 2;
    const int scol = (tid & 3) * 8;
    int ar0 = m0 + srow;      if (ar0 >= M) ar0 = M - 1;
    int ar1 = m0 + 64 + srow; if (ar1 >= M) ar1 = M - 1;
    const unsigned short* Ah = (const unsigned short*)A;
    const float*          Af = (const float*)A;
    const unsigned short* gA0h = Ah + (size_t)ar0 * K + scol;
    const unsigned short* gA1h = Ah + (size_t)ar1 * K + scol;
    const float*          gA0f = Af + (size_t)ar0 * K + scol;
    const float*          gA1f = Af + (size_t)ar1 * K + scol;
    const unsigned short* gB0 = Bt + (size_t)(n0 + srow) * K + scol;
    const unsigned short* gB1 = Bt + (size_t)(n0 + 64 + srow) * K + scol;

    const int wave = tid >> 6, lane = tid & 63;
    const int wr = wave >> 1, wc = wave & 1;
    const int lr = lane & 15;
    const int lk = (lane >> 4) * 8;
    f32x4 acc[4][4] = {};

    for (int k0 = 0; k0 < K; k0 += 32) {
        uint4 a0, a1;
        if (af32) { a0 = packbf8(gA0f + k0); a1 = packbf8(gA1f + k0); }
        else      { a0 = *(const uint4*)(gA0h + k0); a1 = *(const uint4*)(gA1h + k0); }
        uint4 b0 = *(const uint4*)(gB0 + k0);
        uint4 b1 = *(const uint4*)(gB1 + k0);
        __syncthreads();
        *(uint4*)&sA[srow * 32 + scol]        = a0;
        *(uint4*)&sA[(64 + srow) * 32 + scol] = a1;
        *(uint4*)&sB[srow * 32 + scol]        = b0;
        *(uint4*)&sB[(64 + srow) * 32 + scol] = b1;
        __syncthreads();
        bf16x8 aF[4], bF[4];
#pragma unroll
        for (int i = 0; i < 4; i++) aF[i] = *(const bf16x8*)&sA[(wr * 64 + i * 16 + lr) * 32 + lk];
#pragma unroll
        for (int j = 0; j < 4; j++) bF[j] = *(const bf16x8*)&sB[(wc * 64 + j * 16 + lr) * 32 + lk];
#pragma unroll
        for (int i = 0; i < 4; i++)
#pragma unroll
            for (int j = 0; j < 4; j++)
                acc[i][j] = __builtin_amdgcn_mfma_f32_16x16x32_bf16(aF[i], bF[j], acc[i][j], 0, 0, 0);
    }

    float bv[4];
#pragma unroll
    for (int j = 0; j < 4; j++) bv[j] = bf2f(bias[n0 + wc * 64 + j * 16 + lr]);
#pragma unroll
    for (int i = 0; i < 4; i++) {
        int rbase = m0 + wr * 64 + i * 16 + (lane >> 4) * 4;
#pragma unroll
        for (int r = 0; r < 4; r++) {
            int row = rbase + r;
            if (row < M) {
                size_t base = (size_t)row * N + n0 + wc * 64 + lr;
#pragma unroll
                for (int j = 0; j < 4; j++) {
                    float v = acc[i][j][r] + bv[j];
                    if (RELU) v = fmaxf(v, 0.f);
                    C[base + j * 16] = f2bf(v);
                }
            }
        }
    }
}

__global__ __launch_bounds__(256)
void node_att(const unsigned short* __restrict__ h2,
              const void* __restrict__ Wlin,
              const unsigned short* __restrict__ blin,
              const void* __restrict__ Watt,
              const void* __restrict__ attS,
              const void* __restrict__ attD,
              float* __restrict__ hh, float* __restrict__ asrc,
              float* __restrict__ adst, const int* flags) {
    __shared__ float sW[256 * 32];
    __shared__ float sh2[8 * 256];
    __shared__ float sH[8 * 32];
    __shared__ float sHH[8 * 6];
    const int wlf = flags[3], waf = flags[4];
    const int tid = threadIdx.x;
    for (int i = tid; i < 256 * 32; i += 256) sW[i] = ldf(Wlin, i, wlf);
    const int n0 = blockIdx.x * 8;
    {
        int e = tid * 8;
        int r = e >> 8;
        int c = e & 255;
        uint4 v = *(const uint4*)(h2 + (size_t)(n0 + r) * 256 + c);
        float* o = &sh2[r * 256 + c];
        o[0] = __uint_as_float(v.x << 16); o[1] = __uint_as_float(v.x & 0xFFFF0000u);
        o[2] = __uint_as_float(v.y << 16); o[3] = __uint_as_float(v.y & 0xFFFF0000u);
        o[4] = __uint_as_float(v.z << 16); o[5] = __uint_as_float(v.z & 0xFFFF0000u);
        o[6] = __uint_as_float(v.w << 16); o[7] = __uint_as_float(v.w & 0xFFFF0000u);
    }
    __syncthreads();
    const int nl = tid >> 5;
    const int c  = tid & 31;
    float acc = bf2f(blin[c]);
    const float* hrow = &sh2[nl * 256];
#pragma unroll 8
    for (int k = 0; k < 256; k++) acc += hrow[k] * sW[k * 32 + c];
    sH[nl * 32 + c] = acc;
    __syncthreads();
    if (tid < 48) {
        int n = tid / 6, j = tid - (tid / 6) * 6;
        float s = 0.f;
#pragma unroll
        for (int k = 0; k < 32; k++) s += sH[n * 32 + k] * ldf(Watt, k * 6 + j, waf);
        sHH[n * 6 + j] = s;
        hh[(size_t)(n0 + n) * 6 + j] = s;
    }
    __syncthreads();
    if (tid < 16) {
        int n = tid >> 1, hd = tid & 1;
        float s = 0.f, d = 0.f;
#pragma unroll
        for (int cc = 0; cc < 3; cc++) {
            float v = sHH[n * 6 + hd * 3 + cc];
            s += v * ldf(attS, hd * 3 + cc, waf);
            d += v * ldf(attD, hd * 3 + cc, waf);
        }
        asrc[(size_t)(n0 + n) * 2 + hd] = s;
        adst[(size_t)(n0 + n) * 2 + hd] = d;
    }
}

__global__ void init_zero(float* __restrict__ p, int n) {
    int i = blockIdx.x * 256 + threadIdx.x;
    if (i < n) p[i] = 0.f;
}

__global__ void edge_acc(const int* __restrict__ ei,
                         const float* __restrict__ asrc, const float* __restrict__ adst,
                         const float* __restrict__ hh,
                         float* __restrict__ denom, float* __restrict__ num,
                         const int* flags) {
    int idx = blockIdx.x * 256 + threadIdx.x;
    if (idx >= NEDGES + NNODES) return;
    int s, d;
    if (idx < NEDGES) {
        if (flags[5]) {
            const long long* e64 = (const long long*)ei;
            s = (int)e64[idx];
            d = (int)e64[NEDGES + idx];
        } else {
            s = ei[idx];
            d = ei[NEDGES + idx];
        }
    } else {
        s = idx - NEDGES; d = s;
    }
    float2 as = *(const float2*)(asrc + (size_t)s * 2);
    float2 ad = *(const float2*)(adst + (size_t)d * 2);
    float a0 = as.x + ad.x; a0 = a0 > 0.f ? a0 : NEG_SLOPE * a0;
    float a1 = as.y + ad.y; a1 = a1 > 0.f ? a1 : NEG_SLOPE * a1;
    float p0 = __expf(fminf(a0, 60.f));
    float p1 = __expf(fminf(a1, 60.f));
    atomicAdd(&denom[d * 2 + 0], p0);
    atomicAdd(&denom[d * 2 + 1], p1);
    const float* hs = hh + (size_t)s * 6;
    float* nd = num + (size_t)d * 6;
    atomicAdd(&nd[0], p0 * hs[0]);
    atomicAdd(&nd[1], p0 * hs[1]);
    atomicAdd(&nd[2], p0 * hs[2]);
    atomicAdd(&nd[3], p1 * hs[3]);
    atomicAdd(&nd[4], p1 * hs[4]);
    atomicAdd(&nd[5], p1 * hs[5]);
}

__global__ void finalize(const float* __restrict__ num, const float* __restrict__ denom,
                         const unsigned short* __restrict__ bias,
                         void* __restrict__ out, const int* flags) {
    int idx = blockIdx.x * 256 + threadIdx.x;
    if (idx >= NNODES * 3) return;
    int n = idx / 3, c = idx - n * 3;
    float v = 0.5f * (num[n * 6 + c] / denom[n * 2 + 0] +
                      num[n * 6 + 3 + c] / denom[n * 2 + 1]) + bf2f(bias[c]);
    if (flags[0]) ((float*)out)[idx] = v;
    else          ((unsigned short*)out)[idx] = f2bf(v);
}

extern "C" void kernel_launch(void* const* d_in, const int* in_sizes, int n_in,
                              void* d_out, int out_size, void* d_ws, size_t ws_size,
                              hipStream_t stream) {
    const unsigned short* x    = (const unsigned short*)d_in[0];
    const int*            ei   = (const int*)d_in[1];
    const unsigned short* We1  = (const unsigned short*)d_in[2];
    const unsigned short* be1  = (const unsigned short*)d_in[3];
    const unsigned short* We2  = (const unsigned short*)d_in[4];
    const unsigned short* be2  = (const unsigned short*)d_in[5];
    const unsigned short* Wlin = (const unsigned short*)d_in[6];
    const unsigned short* blin = (const unsigned short*)d_in[7];
    const unsigned short* Watt = (const unsigned short*)d_in[8];
    const unsigned short* attS = (const unsigned short*)d_in[9];
    const unsigned short* attD = (const unsigned short*)d_in[10];
    const unsigned short* bias = (const unsigned short*)d_in[11];

    char* ws = (char*)d_ws;
    unsigned short* W1t   = (unsigned short*)(ws + 0);          //     786,432
    unsigned short* W2t   = (unsigned short*)(ws + 786432);     //     262,144
    unsigned short* h2    = (unsigned short*)(ws + 1048576);    //  51,200,000
    float*    hh    = (float*)(ws + 52248576);                  //   2,400,000
    float*    asrc  = (float*)(ws + 54648576);                  //     800,000
    float*    adst  = (float*)(ws + 55448576);                  //     800,000
    float*    denom = (float*)(ws + 56248576);                  //     800,000
    float*    num   = (float*)(ws + 57048576);                  //   2,400,000
    int*      flags = (int*)(ws + 59448576);                    //          64
    unsigned short* h1 = (unsigned short*)(ws + 59448640);      // 102,400,000 (end ~161.8MB)
    (void)ws_size; (void)in_sizes; (void)n_in; (void)out_size;

    detect_dtypes<<<6, 256, 0, stream>>>(x, We1, We2, Wlin, Watt, ei, flags);

    transpose_conv<<<(DIN * DH1 + 255) / 256, 256, 0, stream>>>(We1, W1t, DIN, DH1, flags, 1);
    transpose_conv<<<(DH1 * DH2 + 255) / 256, 256, 0, stream>>>(We2, W2t, DH1, DH2, flags, 2);

    dim3 blk(256);
    dim3 g1((NNODES + 127) / 128, DH1 / 128);
    gemm_bt<true><<<g1, blk, 0, stream>>>(x, W1t, be1, h1, NNODES, DIN, DH1, flags, 0);
    dim3 g2((NNODES + 127) / 128, DH2 / 128);
    gemm_bt<false><<<g2, blk, 0, stream>>>(h1, W2t, be2, h2, NNODES, DH1, DH2, flags, 15);

    node_att<<<NNODES / 8, 256, 0, stream>>>(h2, Wlin, blin, Watt, attS, attD,
                                             hh, asrc, adst, flags);

    init_zero<<<(800000 + 255) / 256, 256, 0, stream>>>(denom, 800000);

    int etot = NEDGES + NNODES;
    edge_acc<<<(etot + 255) / 256, 256, 0, stream>>>(ei, asrc, adst, hh, denom, num, flags);

    finalize<<<(NNODES * 3 + 255) / 256, 256, 0, stream>>>(num, denom, bias, d_out, flags);
}